// Round 15
// baseline (126.720 us; speedup 1.0000x reference)
//
#include <hip/hip_runtime.h>
#include <hip/hip_bf16.h>

// out[n,h,i,j] = logits[i][ clamp(j-i+512, 1, 1023) ],  logits = Q @ R  (per n,h)
// n=4 h=16 L=1024 d=64, table width 1025.
//
// R15 = R12 (74.0 us, verified) + needed-t tile skip ONLY (pret retired: R6/R13/R14
// all show it regresses). Unit at row-base b needs t in [max(1,497-b), min(1023,1535-b)]
// -> ~24% fewer producer tiles on average. Producer keeps R12's direct gathers and
// unroll-4 contiguous loop; the 2 producer waves split [mlo,mhi] contiguously.
// Consumer path, nt stores, 2P+2C @ 256 thr, grid 512, swizzle: IDENTICAL to R12.

#define NH 16
#define LQ 1024
#define DD 64
#define TT 1025
#define MAXP 512
#define PADS 4          // left pad in shorts (multiple of 4 keeps 8B alignment)
#define LSTRIDE2 1036   // shorts; row stride 2072 B
#define UNITS 8

typedef float f32x4 __attribute__((ext_vector_type(4)));
typedef short s16x4 __attribute__((ext_vector_type(4)));
typedef short s16x8 __attribute__((ext_vector_type(8)));

__device__ __forceinline__ short f2bf(float f) {
    __hip_bfloat16 h = __float2bfloat16(f);   // RNE
    return __builtin_bit_cast(short, h);
}
__device__ __forceinline__ float bf2f(short s) {
    return __builtin_bit_cast(float, ((unsigned)(unsigned short)s) << 16);
}

// Writer helper: D = wave-uniform misalignment ((512 - i) & 3), compile-time.
template<int D>
__device__ __forceinline__ void write_chunks(const unsigned short* __restrict__ lrow,
                                             float p1, float p2,
                                             int i, int l, float* __restrict__ orow) {
    #pragma unroll
    for (int c = 0; c < 4; ++c) {
        const int j0 = c * 256 + 4 * l;
        const int t0 = j0 - i + MAXP;
        int colA = PADS + t0 - D;                 // = PADS + (t0 & ~3), 8B aligned
        colA = colA < 0 ? 0 : (colA > PADS + LQ ? PADS + LQ : colA);  // clamped lanes: value unused
        s16x4 A = *(const s16x4*)(lrow + colA);
        s16x4 B = {0, 0, 0, 0};
        if (D) B = *(const s16x4*)(lrow + colA + 4);
        f32x4 v;
        #pragma unroll
        for (int e = 0; e < 4; ++e) {
            const int t = t0 + e;
            const float in = bf2f((D + e < 4) ? A[D + e] : B[D + e - 4]);
            v[e] = t < 1 ? p1 : (t > LQ - 1 ? p2 : in);
        }
        __builtin_nontemporal_store(v, (f32x4*)(orow + j0));   // nt (R7/R8 A/B: +8%)
    }
}

// grid 512 (1D), block 256 = 4 waves (2 producers + 2 consumers), 8 units/block.
__global__ __launch_bounds__(256, 2) void lpb_pc(const float* __restrict__ Q,
                                                 const float* __restrict__ R,
                                                 float* __restrict__ out) {
    __shared__ unsigned short lg[2][16][LSTRIDE2];   // 2-slot pipeline, 66.3 KB

    // XCD-chunked bijective swizzle (512 % 8 == 0): XCD k gets nh in [8k, 8k+8)
    const int bidx = blockIdx.x;
    const int swz  = (bidx & 7) * 64 + (bidx >> 3);
    const int nh   = swz >> 3;
    const int ibg  = swz & 7;
    const int h    = nh & (NH - 1);

    const int tid = threadIdx.x;
    const int w = tid >> 6, l = tid & 63;
    const int n = l & 15, g = l >> 4;

    const float* rbase = R + (size_t)(h * DD + 8 * g) * TT;

    #pragma unroll 1
    for (int rnd = 0; rnd <= UNITS; ++rnd) {
        if (w < 2) {
            if (rnd < UNITS) {
                // ---- produce unit rnd into lg[rnd&1], only needed t-tiles
                const int b   = (ibg * UNITS + rnd) * 16;
                const int tlo = 497 - b < 1 ? 1 : 497 - b;
                const int thi = 1535 - b > 1023 ? 1023 : 1535 - b;
                const int mlo = tlo >> 4, mhi = thi >> 4;
                const int cnt  = mhi - mlo + 1;
                const int half = (cnt + 1) >> 1;
                const int mstart = mlo + w * half;              // wave w's contiguous range
                const int mcnt   = w ? cnt - half : half;

                const float* qrow = Q + ((size_t)nh * LQ + (b + n)) * DD + 8 * g;
                s16x8 qf[2];    // B-operand: lane (n,g) holds Q[b+n][kh*32 + 8g + e]
                #pragma unroll
                for (int kh = 0; kh < 2; ++kh) {
                    f32x4 a  = *(const f32x4*)(qrow + kh * 32);
                    f32x4 bb = *(const f32x4*)(qrow + kh * 32 + 4);
                    #pragma unroll
                    for (int e = 0; e < 4; ++e) { qf[kh][e] = f2bf(a[e]); qf[kh][4 + e] = f2bf(bb[e]); }
                }
                unsigned short (*buf)[LSTRIDE2] = lg[rnd & 1];
                #pragma unroll 4
                for (int k = 0; k < mcnt; ++k) {
                    const int tb = (mstart + k) << 4;
                    const float* rc = rbase + tb + n;
                    s16x8 rf0, rf1;   // A-operand: lane (n,g) holds R[h][8g+e][tb+n]
                    #pragma unroll
                    for (int e = 0; e < 8; ++e) {
                        rf0[e] = f2bf(rc[(size_t)e * TT]);
                        rf1[e] = f2bf(rc[(size_t)(32 + e) * TT]);
                    }
                    f32x4 acc = (f32x4){0.f, 0.f, 0.f, 0.f};
                    acc = __builtin_amdgcn_mfma_f32_16x16x32_bf16(rf0, qf[0], acc, 0, 0, 0);
                    acc = __builtin_amdgcn_mfma_f32_16x16x32_bf16(rf1, qf[1], acc, 0, 0, 0);
                    // D: col=n -> i-local, row=4g+s -> t=tb+4g+s: pack bf16, b64 write
                    s16x4 hv;
                    #pragma unroll
                    for (int s = 0; s < 4; ++s) hv[s] = f2bf(acc[s]);
                    *(s16x4*)&buf[n][PADS + tb + 4 * g] = hv;
                }
            }
        } else {
            if (rnd > 0) {
                // ---- consume unit rnd-1 from lg[(rnd-1)&1]: wave (w-2) owns 8 rows
                const int u = rnd - 1;
                const int ibase = (ibg * UNITS + u) * 16;
                unsigned short (*buf)[LSTRIDE2] = lg[u & 1];
                const int cw = w - 2;
                #pragma unroll 1
                for (int rr = 0; rr < 8; ++rr) {
                    const int il = cw * 8 + rr;
                    const int i  = ibase + il;
                    const unsigned short* lrow = &buf[il][0];
                    const float p1 = bf2f(lrow[PADS + 1]);          // left clamp constant
                    const float p2 = bf2f(lrow[PADS + LQ - 1]);     // right clamp constant
                    float* orow = out + ((size_t)nh * LQ + i) * LQ;
                    switch ((MAXP - i) & 3) {                       // row-uniform shift
                        case 0: write_chunks<0>(lrow, p1, p2, i, l, orow); break;
                        case 1: write_chunks<1>(lrow, p1, p2, i, l, orow); break;
                        case 2: write_chunks<2>(lrow, p1, p2, i, l, orow); break;
                        default: write_chunks<3>(lrow, p1, p2, i, l, orow); break;
                    }
                }
            }
        }
        __syncthreads();   // orders: producer writes(rnd) -> consumer reads(rnd+1);
                           // consumer reads(rnd) -> producer overwrite(rnd+1)
    }
}

extern "C" void kernel_launch(void* const* d_in, const int* in_sizes, int n_in,
                              void* d_out, int out_size, void* d_ws, size_t ws_size,
                              hipStream_t stream) {
    const float* Q = (const float*)d_in[0];
    const float* R = (const float*)d_in[1];
    float* out = (float*)d_out;

    lpb_pc<<<dim3(512), 256, 0, stream>>>(Q, R, out);
}

// Round 16
// 93.661 us; speedup vs baseline: 1.3530x; 1.3530x over previous
//
#include <hip/hip_runtime.h>
#include <hip/hip_bf16.h>

// out[n,h,i,j] = logits[i][ clamp(j-i+512, 1, 1023) ],  logits = Q @ R  (per n,h)
// n=4 h=16 L=1024 d=64, table width 1025.
//
// R16 = R12 (74.0 us, verified) with ONE change: consumer stores are PLAIN f32x4
// (was nontemporal). Clean A/B of store mode inside the P/C structure —
// R8's nt-win was measured in the bursty convoy structure; R13's plain test was
// confounded (pret + 512 thr). Memsets prove plain+L2-combining = 6.9 TB/s vs
// nt's 5.0 (R11 probes); question is which wins under continuous issue + reads.
// Producer, 2P+2C @ 256 thr, grid 512, swizzle, barriers: byte-identical to R12.

#define NH 16
#define LQ 1024
#define DD 64
#define TT 1025
#define MAXP 512
#define PADS 4          // left pad in shorts (multiple of 4 keeps 8B alignment)
#define LSTRIDE2 1036   // shorts; row stride 2072 B
#define UNITS 8

typedef float f32x4 __attribute__((ext_vector_type(4)));
typedef short s16x4 __attribute__((ext_vector_type(4)));
typedef short s16x8 __attribute__((ext_vector_type(8)));

__device__ __forceinline__ short f2bf(float f) {
    __hip_bfloat16 h = __float2bfloat16(f);   // RNE
    return __builtin_bit_cast(short, h);
}
__device__ __forceinline__ float bf2f(short s) {
    return __builtin_bit_cast(float, ((unsigned)(unsigned short)s) << 16);
}

// Writer helper: D = wave-uniform misalignment ((512 - i) & 3), compile-time.
template<int D>
__device__ __forceinline__ void write_chunks(const unsigned short* __restrict__ lrow,
                                             float p1, float p2,
                                             int i, int l, float* __restrict__ orow) {
    #pragma unroll
    for (int c = 0; c < 4; ++c) {
        const int j0 = c * 256 + 4 * l;
        const int t0 = j0 - i + MAXP;
        int colA = PADS + t0 - D;                 // = PADS + (t0 & ~3), 8B aligned
        colA = colA < 0 ? 0 : (colA > PADS + LQ ? PADS + LQ : colA);  // clamped lanes: value unused
        s16x4 A = *(const s16x4*)(lrow + colA);
        s16x4 B = {0, 0, 0, 0};
        if (D) B = *(const s16x4*)(lrow + colA + 4);
        f32x4 v;
        #pragma unroll
        for (int e = 0; e < 4; ++e) {
            const int t = t0 + e;
            const float in = bf2f((D + e < 4) ? A[D + e] : B[D + e - 4]);
            v[e] = t < 1 ? p1 : (t > LQ - 1 ? p2 : in);
        }
        *(f32x4*)(orow + j0) = v;                 // PLAIN store (R16's single change)
    }
}

// grid 512 (1D), block 256 = 4 waves (2 producers + 2 consumers), 8 units/block.
__global__ __launch_bounds__(256, 2) void lpb_pc(const float* __restrict__ Q,
                                                 const float* __restrict__ R,
                                                 float* __restrict__ out) {
    __shared__ unsigned short lg[2][16][LSTRIDE2];   // 2-slot pipeline, 66.3 KB

    // XCD-chunked bijective swizzle (512 % 8 == 0): XCD k gets nh in [8k, 8k+8)
    const int bidx = blockIdx.x;
    const int swz  = (bidx & 7) * 64 + (bidx >> 3);
    const int nh   = swz >> 3;
    const int ibg  = swz & 7;
    const int h    = nh & (NH - 1);

    const int tid = threadIdx.x;
    const int w = tid >> 6, l = tid & 63;
    const int n = l & 15, g = l >> 4;

    const float* rbase = R + (size_t)(h * DD + 8 * g) * TT;

    #pragma unroll 1
    for (int rnd = 0; rnd <= UNITS; ++rnd) {
        if (w < 2) {
            if (rnd < UNITS) {
                // ---- produce unit rnd into lg[rnd&1]: wave w covers t in [512w, 512w+512)
                const int ibase = (ibg * UNITS + rnd) * 16;
                const float* qrow = Q + ((size_t)nh * LQ + (ibase + n)) * DD + 8 * g;
                s16x8 qf[2];    // B-operand: lane (n,g) holds Q[ibase+n][kh*32 + 8g + e]
                #pragma unroll
                for (int kh = 0; kh < 2; ++kh) {
                    f32x4 a = *(const f32x4*)(qrow + kh * 32);
                    f32x4 b = *(const f32x4*)(qrow + kh * 32 + 4);
                    #pragma unroll
                    for (int e = 0; e < 4; ++e) { qf[kh][e] = f2bf(a[e]); qf[kh][4 + e] = f2bf(b[e]); }
                }
                unsigned short (*buf)[LSTRIDE2] = lg[rnd & 1];
                #pragma unroll 4
                for (int mt = 0; mt < 32; ++mt) {
                    const int tb = w * 512 + mt * 16;
                    const float* rc = rbase + tb + n;
                    s16x8 rf0, rf1;   // A-operand: lane (n,g) holds R[h][8g+e][tb+n]
                    #pragma unroll
                    for (int e = 0; e < 8; ++e) {
                        rf0[e] = f2bf(rc[(size_t)e * TT]);
                        rf1[e] = f2bf(rc[(size_t)(32 + e) * TT]);
                    }
                    f32x4 acc = (f32x4){0.f, 0.f, 0.f, 0.f};
                    acc = __builtin_amdgcn_mfma_f32_16x16x32_bf16(rf0, qf[0], acc, 0, 0, 0);
                    acc = __builtin_amdgcn_mfma_f32_16x16x32_bf16(rf1, qf[1], acc, 0, 0, 0);
                    // D: col=n -> i-local, row=4g+s -> t=tb+4g+s: pack bf16, b64 write
                    s16x4 hv;
                    #pragma unroll
                    for (int s = 0; s < 4; ++s) hv[s] = f2bf(acc[s]);
                    *(s16x4*)&buf[n][PADS + tb + 4 * g] = hv;
                }
            }
        } else {
            if (rnd > 0) {
                // ---- consume unit rnd-1 from lg[(rnd-1)&1]: wave (w-2) owns 8 rows
                const int u = rnd - 1;
                const int ibase = (ibg * UNITS + u) * 16;
                unsigned short (*buf)[LSTRIDE2] = lg[u & 1];
                const int cw = w - 2;
                #pragma unroll 1
                for (int rr = 0; rr < 8; ++rr) {
                    const int il = cw * 8 + rr;
                    const int i  = ibase + il;
                    const unsigned short* lrow = &buf[il][0];
                    const float p1 = bf2f(lrow[PADS + 1]);          // left clamp constant
                    const float p2 = bf2f(lrow[PADS + LQ - 1]);     // right clamp constant
                    float* orow = out + ((size_t)nh * LQ + i) * LQ;
                    switch ((MAXP - i) & 3) {                       // row-uniform shift
                        case 0: write_chunks<0>(lrow, p1, p2, i, l, orow); break;
                        case 1: write_chunks<1>(lrow, p1, p2, i, l, orow); break;
                        case 2: write_chunks<2>(lrow, p1, p2, i, l, orow); break;
                        default: write_chunks<3>(lrow, p1, p2, i, l, orow); break;
                    }
                }
            }
        }
        __syncthreads();   // orders: producer writes(rnd) -> consumer reads(rnd+1);
                           // consumer reads(rnd) -> producer overwrite(rnd+1)
    }
}

extern "C" void kernel_launch(void* const* d_in, const int* in_sizes, int n_in,
                              void* d_out, int out_size, void* d_ws, size_t ws_size,
                              hipStream_t stream) {
    const float* Q = (const float*)d_in[0];
    const float* R = (const float*)d_in[1];
    float* out = (float*)d_out;

    lpb_pc<<<dim3(512), 256, 0, stream>>>(Q, R, out);
}

// Round 17
// 74.664 us; speedup vs baseline: 1.6972x; 1.2544x over previous
//
#include <hip/hip_runtime.h>
#include <hip/hip_bf16.h>

// out[n,h,i,j] = logits[i][ clamp(j-i+512, 1, 1023) ],  logits = Q @ R  (per n,h)
// n=4 h=16 L=1024 d=64, table width 1025.
//
// R17 = R12 (74.0 us) scaled to 512-thr blocks: 4 producer + 4 consumer waves.
//   - producer wave w: t in [256w, 256w+256), 16 tiles compile-time, unroll 4
//     (exact R5/R7 loop shape; R15 showed runtime trip counts kill pipelining)
//   - consumer wave: 4 rows each (same write_chunks, nt stores — R16 confirmed nt)
//   - LDS 2-slot pipeline, grid 512, XCD swizzle, barriers: byte-identical to R12
// Model: P 7.5 -> ~3.75 us/round, store-waves/CU 4 -> 8; C floor 6.4 us/round.

#define NH 16
#define LQ 1024
#define DD 64
#define TT 1025
#define MAXP 512
#define PADS 4          // left pad in shorts (multiple of 4 keeps 8B alignment)
#define LSTRIDE2 1036   // shorts; row stride 2072 B
#define UNITS 8

typedef float f32x4 __attribute__((ext_vector_type(4)));
typedef short s16x4 __attribute__((ext_vector_type(4)));
typedef short s16x8 __attribute__((ext_vector_type(8)));

__device__ __forceinline__ short f2bf(float f) {
    __hip_bfloat16 h = __float2bfloat16(f);   // RNE
    return __builtin_bit_cast(short, h);
}
__device__ __forceinline__ float bf2f(short s) {
    return __builtin_bit_cast(float, ((unsigned)(unsigned short)s) << 16);
}

// Writer helper: D = wave-uniform misalignment ((512 - i) & 3), compile-time.
template<int D>
__device__ __forceinline__ void write_chunks(const unsigned short* __restrict__ lrow,
                                             float p1, float p2,
                                             int i, int l, float* __restrict__ orow) {
    #pragma unroll
    for (int c = 0; c < 4; ++c) {
        const int j0 = c * 256 + 4 * l;
        const int t0 = j0 - i + MAXP;
        int colA = PADS + t0 - D;                 // = PADS + (t0 & ~3), 8B aligned
        colA = colA < 0 ? 0 : (colA > PADS + LQ ? PADS + LQ : colA);  // clamped lanes: value unused
        s16x4 A = *(const s16x4*)(lrow + colA);
        s16x4 B = {0, 0, 0, 0};
        if (D) B = *(const s16x4*)(lrow + colA + 4);
        f32x4 v;
        #pragma unroll
        for (int e = 0; e < 4; ++e) {
            const int t = t0 + e;
            const float in = bf2f((D + e < 4) ? A[D + e] : B[D + e - 4]);
            v[e] = t < 1 ? p1 : (t > LQ - 1 ? p2 : in);
        }
        __builtin_nontemporal_store(v, (f32x4*)(orow + j0));   // nt (R16: plain is -20us)
    }
}

// grid 512 (1D), block 512 = 8 waves (4 producers + 4 consumers), 8 units/block.
__global__ __launch_bounds__(512, 4) void lpb_pc(const float* __restrict__ Q,
                                                 const float* __restrict__ R,
                                                 float* __restrict__ out) {
    __shared__ unsigned short lg[2][16][LSTRIDE2];   // 2-slot pipeline, 66.3 KB

    // XCD-chunked bijective swizzle (512 % 8 == 0): XCD k gets nh in [8k, 8k+8)
    const int bidx = blockIdx.x;
    const int swz  = (bidx & 7) * 64 + (bidx >> 3);
    const int nh   = swz >> 3;
    const int ibg  = swz & 7;
    const int h    = nh & (NH - 1);

    const int tid = threadIdx.x;
    const int w = tid >> 6, l = tid & 63;
    const int n = l & 15, g = l >> 4;

    const float* rbase = R + (size_t)(h * DD + 8 * g) * TT;

    #pragma unroll 1
    for (int rnd = 0; rnd <= UNITS; ++rnd) {
        if (w < 4) {
            if (rnd < UNITS) {
                // ---- produce unit rnd into lg[rnd&1]: wave w covers t in [256w, 256w+256)
                const int ibase = (ibg * UNITS + rnd) * 16;
                const float* qrow = Q + ((size_t)nh * LQ + (ibase + n)) * DD + 8 * g;
                s16x8 qf[2];    // B-operand: lane (n,g) holds Q[ibase+n][kh*32 + 8g + e]
                #pragma unroll
                for (int kh = 0; kh < 2; ++kh) {
                    f32x4 a = *(const f32x4*)(qrow + kh * 32);
                    f32x4 b = *(const f32x4*)(qrow + kh * 32 + 4);
                    #pragma unroll
                    for (int e = 0; e < 4; ++e) { qf[kh][e] = f2bf(a[e]); qf[kh][4 + e] = f2bf(b[e]); }
                }
                unsigned short (*buf)[LSTRIDE2] = lg[rnd & 1];
                #pragma unroll 4
                for (int mt = 0; mt < 16; ++mt) {
                    const int tb = w * 256 + mt * 16;
                    const float* rc = rbase + tb + n;
                    s16x8 rf0, rf1;   // A-operand: lane (n,g) holds R[h][8g+e][tb+n]
                    #pragma unroll
                    for (int e = 0; e < 8; ++e) {
                        rf0[e] = f2bf(rc[(size_t)e * TT]);
                        rf1[e] = f2bf(rc[(size_t)(32 + e) * TT]);
                    }
                    f32x4 acc = (f32x4){0.f, 0.f, 0.f, 0.f};
                    acc = __builtin_amdgcn_mfma_f32_16x16x32_bf16(rf0, qf[0], acc, 0, 0, 0);
                    acc = __builtin_amdgcn_mfma_f32_16x16x32_bf16(rf1, qf[1], acc, 0, 0, 0);
                    // D: col=n -> i-local, row=4g+s -> t=tb+4g+s: pack bf16, b64 write
                    s16x4 hv;
                    #pragma unroll
                    for (int s = 0; s < 4; ++s) hv[s] = f2bf(acc[s]);
                    *(s16x4*)&buf[n][PADS + tb + 4 * g] = hv;
                }
            }
        } else {
            if (rnd > 0) {
                // ---- consume unit rnd-1 from lg[(rnd-1)&1]: wave (w-4) owns 4 rows
                const int u = rnd - 1;
                const int ibase = (ibg * UNITS + u) * 16;
                unsigned short (*buf)[LSTRIDE2] = lg[u & 1];
                const int cw = w - 4;
                #pragma unroll 1
                for (int rr = 0; rr < 4; ++rr) {
                    const int il = cw * 4 + rr;
                    const int i  = ibase + il;
                    const unsigned short* lrow = &buf[il][0];
                    const float p1 = bf2f(lrow[PADS + 1]);          // left clamp constant
                    const float p2 = bf2f(lrow[PADS + LQ - 1]);     // right clamp constant
                    float* orow = out + ((size_t)nh * LQ + i) * LQ;
                    switch ((MAXP - i) & 3) {                       // row-uniform shift
                        case 0: write_chunks<0>(lrow, p1, p2, i, l, orow); break;
                        case 1: write_chunks<1>(lrow, p1, p2, i, l, orow); break;
                        case 2: write_chunks<2>(lrow, p1, p2, i, l, orow); break;
                        default: write_chunks<3>(lrow, p1, p2, i, l, orow); break;
                    }
                }
            }
        }
        __syncthreads();   // orders: producer writes(rnd) -> consumer reads(rnd+1);
                           // consumer reads(rnd) -> producer overwrite(rnd+1)
    }
}

extern "C" void kernel_launch(void* const* d_in, const int* in_sizes, int n_in,
                              void* d_out, int out_size, void* d_ws, size_t ws_size,
                              hipStream_t stream) {
    const float* Q = (const float*)d_in[0];
    const float* R = (const float*)d_in[1];
    float* out = (float*)d_out;

    lpb_pc<<<dim3(512), 512, 0, stream>>>(Q, R, out);
}